// Round 3
// baseline (490.870 us; speedup 1.0000x reference)
//
#include <hip/hip_runtime.h>

typedef unsigned short u16;
typedef unsigned int u32;
typedef __attribute__((ext_vector_type(8))) short short8;
typedef __attribute__((ext_vector_type(4))) float f32x4;
typedef __attribute__((ext_vector_type(2))) float f32x2;

__device__ __forceinline__ float b2f(u16 v) { return __uint_as_float(((u32)v) << 16); }
__device__ __forceinline__ u16 f2b(float f) {
  u32 x = __float_as_uint(f);
  return (u16)((x + 0x7FFFu + ((x >> 16) & 1u)) >> 16);  // round-nearest-even
}

// ---------------- runtime dtype detection (deterministic, graph-safe) ----------------
// flags[0]=1 if float inputs are bf16, 0 if fp32.
// flags[1]=1 if edge_indices are int64, 0 if int32.
__global__ void detect_kernel(const u16* __restrict__ X16, const int* __restrict__ EIDX,
                              int* __restrict__ flags) {
  if (threadIdx.x != 0 || blockIdx.x != 0) return;
  int isb = 1;
  for (int i = 0; i < 32; i += 2) {  // even u16s: bf16 values, or fp32 low-mantissa halves
    const u16 v = X16[i];
    const u32 hb = (v >> 8) & 0x7f;  // top 7 bits of exponent, sign stripped
    if (!(v == 0 || (hb >= 0x32 && hb <= 0x41))) isb = 0;  // |x| outside [2^-27, 32)
  }
  int i64 = 1;
  for (int i = 1; i < 32; i += 2)  // int64 -> every odd int32 word is a zero high-word
    if (EIDX[i] != 0) i64 = 0;
  flags[0] = isb;
  flags[1] = i64;
}

__global__ void sentinel_kernel(float* out) {
  if (threadIdx.x == 0 && blockIdx.x == 0) out[0] = 1.0e6f;  // ws too small marker
}

// ---------------- h = X @ W^T + b  (fp32 MFMA accum, bf16 H) ----------------
// LDS: 128x128 u16 = exactly 64 KB. XOR chunk swizzle: logical (row, chunk c of 8 u16)
// stored at chunk (c ^ (row & 15)) -> B-fragment ds_read_b128 is perfectly bank-balanced.
__global__ __launch_bounds__(256) void gemm_kernel(const void* __restrict__ Xv,
                                                   const void* __restrict__ Wv,
                                                   const void* __restrict__ Bv,
                                                   u16* __restrict__ H, int M,
                                                   const int* __restrict__ flags) {
  const int isb = flags[0];
  __shared__ u16 lw[128 * 128];
  const int tid = threadIdx.x;
  {
    const int row = tid >> 1, half = tid & 1;
    if (isb) {
      const u16* src = (const u16*)Wv + row * 128;
#pragma unroll
      for (int i = 0; i < 8; ++i) {
        const int c = half * 8 + i;  // logical chunk [0,16)
        *(short8*)&lw[row * 128 + ((c ^ (row & 15)) * 8)] = *(const short8*)(src + c * 8);
      }
    } else {
      const float* src = (const float*)Wv + row * 128;
#pragma unroll
      for (int i = 0; i < 8; ++i) {
        const int c = half * 8 + i;
        f32x4 a = *(const f32x4*)(src + c * 8);
        f32x4 b = *(const f32x4*)(src + c * 8 + 4);
        short8 o;
#pragma unroll
        for (int j = 0; j < 4; ++j) { o[j] = (short)f2b(a[j]); o[j + 4] = (short)f2b(b[j]); }
        *(short8*)&lw[row * 128 + ((c ^ (row & 15)) * 8)] = o;
      }
    }
  }
  __syncthreads();

  const int wave = tid >> 6, lane = tid & 63;
  const int q = lane >> 4, r = lane & 15;
  const int mfrag = blockIdx.x * 64 + wave * 16 + r;  // A-frag: m = lane&15, k = q*8+j
  const long msafe = (mfrag < M) ? mfrag : 0;

  f32x4 acc[8];
#pragma unroll
  for (int i = 0; i < 8; ++i) acc[i] = (f32x4){0.f, 0.f, 0.f, 0.f};

#pragma unroll
  for (int kk = 0; kk < 4; ++kk) {
    short8 a;
    if (isb) {
      a = *(const short8*)((const u16*)Xv + msafe * 128 + kk * 32 + q * 8);
    } else {
      const float* xp = (const float*)Xv + msafe * 128 + kk * 32 + q * 8;
      f32x4 x0 = *(const f32x4*)xp;
      f32x4 x1 = *(const f32x4*)(xp + 4);
#pragma unroll
      for (int j = 0; j < 4; ++j) { a[j] = (short)f2b(x0[j]); a[j + 4] = (short)f2b(x1[j]); }
    }
#pragma unroll
    for (int nt = 0; nt < 8; ++nt) {
      // B-frag: n = lane&15 = r (row of W), k = q*8+j; chunk = kk*4+q, swizzled by row&15=r
      short8 b = *(const short8*)&lw[(nt * 16 + r) * 128 + (((kk * 4 + q) ^ r) * 8)];
      acc[nt] = __builtin_amdgcn_mfma_f32_16x16x32_bf16(a, b, acc[nt], 0, 0, 0);
    }
  }

  // C/D: col(lane&15) = n within tile, row = q*4 + reg = m
  const int mbase = blockIdx.x * 64 + wave * 16 + q * 4;
#pragma unroll
  for (int nt = 0; nt < 8; ++nt) {
    const int n = nt * 16 + r;
    const float bn = isb ? b2f(((const u16*)Bv)[n]) : ((const float*)Bv)[n];
#pragma unroll
    for (int rr = 0; rr < 4; ++rr) {
      const int m = mbase + rr;
      if (m < M) H[(long)m * 128 + n] = f2b(acc[nt][rr] + bn);
    }
  }
}

// ---------------- per-(node,head) attention projections ----------------
__global__ __launch_bounds__(256) void alpha_kernel(const u16* __restrict__ H,
                                                    const void* __restrict__ ATTv,
                                                    float* __restrict__ a_t,
                                                    float* __restrict__ a_s, int N,
                                                    const int* __restrict__ flags) {
  const int isb = flags[0];
  const int tid = blockIdx.x * 256 + threadIdx.x;
  if (tid >= N * 4) return;
  const int node = tid >> 2, head = tid & 3;
  const u16* hp = H + (long)node * 128 + head * 32;
  const u16* a16 = (const u16*)ATTv + head * 64;
  const float* a32 = (const float*)ATTv + head * 64;
  float st = 0.f, ss = 0.f;
#pragma unroll
  for (int v = 0; v < 4; ++v) {
    short8 hv = *(const short8*)(hp + v * 8);
#pragma unroll
    for (int j = 0; j < 8; ++j) {
      const int k = v * 8 + j;
      const float x = b2f((u16)hv[j]);
      const float wt = isb ? b2f(a16[k]) : a32[k];
      const float ws = isb ? b2f(a16[32 + k]) : a32[32 + k];
      st += x * wt;
      ss += x * ws;
    }
  }
  a_t[tid] = st;
  a_s[tid] = ss;
}

// ---------------- per-edge: softmax denom + in-degree ----------------
// e <= emax globally so leaky_relu(e-emax) = 0.01*(e-emax); the exp(-0.01*emax)
// factor cancels between att and denom (EPS perturbation ~4e-10 relative).
__global__ __launch_bounds__(256) void edge_kernel(const int* __restrict__ EIDX,
                                                   const f32x4* __restrict__ a_t,
                                                   const f32x4* __restrict__ a_s,
                                                   float* __restrict__ denom,
                                                   int* __restrict__ cnt, int E,
                                                   const int* __restrict__ flags) {
  const int i64 = flags[1];
  const int e = blockIdx.x * 256 + threadIdx.x;
  if (e >= E) return;
  const int s = i64 ? EIDX[2 * e] : EIDX[e];
  const int t = i64 ? EIDX[2 * E + 2 * e] : EIDX[E + e];
  const f32x4 at = a_t[t], as = a_s[s];
#pragma unroll
  for (int h = 0; h < 4; ++h) atomicAdd(&denom[t * 4 + h], __expf(0.01f * (at[h] + as[h])));
  atomicAdd(&cnt[t], 1);
}

// ---------------- counting-sort scan (3 phases) ----------------
__global__ __launch_bounds__(256) void scan_bsums(const int* __restrict__ cnt,
                                                  int* __restrict__ bsum, int N) {
  __shared__ int s[256];
  const int i = blockIdx.x * 256 + threadIdx.x;
  s[threadIdx.x] = (i < N) ? cnt[i] : 0;
  __syncthreads();
  for (int o = 128; o > 0; o >>= 1) {
    if (threadIdx.x < o) s[threadIdx.x] += s[threadIdx.x + o];
    __syncthreads();
  }
  if (threadIdx.x == 0) bsum[blockIdx.x] = s[0];
}

__global__ __launch_bounds__(512) void scan_scan(int* bsum, int nb) {
  __shared__ int s[512];
  const int t = threadIdx.x;
  s[t] = (t < nb) ? bsum[t] : 0;
  __syncthreads();
  for (int o = 1; o < 512; o <<= 1) {
    const int x = (t >= o) ? s[t - o] : 0;
    __syncthreads();
    s[t] += x;
    __syncthreads();
  }
  if (t < nb) bsum[t] = (t == 0) ? 0 : s[t - 1];  // exclusive
}

__global__ __launch_bounds__(256) void scan_final(const int* __restrict__ cnt,
                                                  const int* __restrict__ bbase,
                                                  int* __restrict__ offsets,
                                                  int* __restrict__ cursor, int N) {
  __shared__ int s[256];
  const int i = blockIdx.x * 256 + threadIdx.x;
  const int t = threadIdx.x;
  const int v = (i < N) ? cnt[i] : 0;
  s[t] = v;
  __syncthreads();
  for (int o = 1; o < 256; o <<= 1) {
    const int x = (t >= o) ? s[t - o] : 0;
    __syncthreads();
    s[t] += x;
    __syncthreads();
  }
  if (i < N) {
    const int excl = s[t] - v + bbase[blockIdx.x];
    offsets[i] = excl;
    cursor[i] = excl;
  }
}

// ---------------- bucket edges by target ----------------
__global__ __launch_bounds__(256) void scatter_kernel(const int* __restrict__ EIDX,
                                                      int* __restrict__ cursor,
                                                      int* __restrict__ s_src, int E,
                                                      const int* __restrict__ flags) {
  const int i64 = flags[1];
  const int e = blockIdx.x * 256 + threadIdx.x;
  if (e >= E) return;
  const int s = i64 ? EIDX[2 * e] : EIDX[e];
  const int t = i64 ? EIDX[2 * E + 2 * e] : EIDX[E + e];
  const int pos = atomicAdd(&cursor[t], 1);
  s_src[pos] = s;
}

// ---------------- per-node aggregation + head mean ----------------
// wave per node; lane holds channels {2*lane, 2*lane+1} of h (head = lane>>4).
__global__ __launch_bounds__(256) void agg_kernel(const u16* __restrict__ H,
                                                  const int* __restrict__ s_src,
                                                  const float* __restrict__ a_t,
                                                  const float* __restrict__ a_s,
                                                  const int* __restrict__ offsets,
                                                  const int* __restrict__ cnt,
                                                  const float* __restrict__ denom,
                                                  void* __restrict__ OUTv, int N,
                                                  const int* __restrict__ flags) {
  const int isb = flags[0];
  const int node = blockIdx.x * 4 + (threadIdx.x >> 6);
  if (node >= N) return;  // wave-uniform exit
  const int lane = threadIdx.x & 63;
  const int h = lane >> 4;
  const int start = offsets[node];
  const int deg = cnt[node];
  const float inv = 1.f / (denom[node * 4 + h] + 1e-8f);
  const float atv = a_t[node * 4 + h];
  float acc0 = 0.f, acc1 = 0.f;
  for (int i = 0; i < deg; ++i) {
    const int src = s_src[start + i];
    const float wv = __expf(0.01f * (atv + a_s[src * 4 + h])) * inv;
    const u32 hv = *(const u32*)(H + (size_t)src * 128 + lane * 2);
    acc0 += wv * b2f((u16)(hv & 0xFFFFu));
    acc1 += wv * b2f((u16)(hv >> 16));
  }
  // mean over 4 heads: lanes {c, c+16, c+32, c+48} hold the same channel pair
  acc0 += __shfl_xor(acc0, 16);
  acc0 += __shfl_xor(acc0, 32);
  acc1 += __shfl_xor(acc1, 16);
  acc1 += __shfl_xor(acc1, 32);
  if (lane < 16) {
    if (isb) {
      const u32 o = (u32)f2b(acc0 * 0.25f) | ((u32)f2b(acc1 * 0.25f) << 16);
      *(u32*)((u16*)OUTv + (size_t)node * 32 + lane * 2) = o;
    } else {
      *(f32x2*)((float*)OUTv + (size_t)node * 32 + lane * 2) = (f32x2){acc0 * 0.25f, acc1 * 0.25f};
    }
  }
}

extern "C" void kernel_launch(void* const* d_in, const int* in_sizes, int n_in,
                              void* d_out, int out_size, void* d_ws, size_t ws_size,
                              hipStream_t stream) {
  const void* X = d_in[0];
  const int* EIDX = (const int*)d_in[1];
  const void* W = d_in[2];
  const void* B = d_in[3];
  const void* ATT = d_in[4];

  const int N = in_sizes[0] / 128;
  const int E = in_sizes[1] / 2;

  char* ws = (char*)d_ws;
  size_t off = 0;
  auto alloc = [&](size_t bytes) {
    void* p = ws + off;
    off += (bytes + 255) & ~(size_t)255;
    return p;
  };
  u16* H = (u16*)alloc((size_t)N * 128 * 2);        // 25.6 MB
  float* a_t = (float*)alloc((size_t)N * 4 * 4);    // 1.6 MB
  float* a_s = (float*)alloc((size_t)N * 4 * 4);    // 1.6 MB
  float* denom = (float*)alloc((size_t)N * 4 * 4);  // 1.6 MB
  int* cnt = (int*)alloc((size_t)N * 4);            // 0.4 MB
  int* bsum = (int*)alloc(4096);
  int* offsets = (int*)alloc((size_t)N * 4);
  int* cursor = (int*)alloc((size_t)N * 4);
  int* s_src = (int*)alloc((size_t)E * 4);          // 3.2 MB
  int* flags = (int*)alloc(256);                    // total ~34.9 MB

  if (ws_size < off) {  // diagnostic path: absmax would show ~1e6, not NaN
    hipMemsetAsync(d_out, 0, (size_t)out_size * 2, stream);
    sentinel_kernel<<<1, 64, 0, stream>>>((float*)d_out);
    return;
  }

  hipMemsetAsync(denom, 0, (size_t)N * 4 * 4, stream);
  hipMemsetAsync(cnt, 0, (size_t)N * 4, stream);

  detect_kernel<<<1, 64, 0, stream>>>((const u16*)X, EIDX, flags);
  gemm_kernel<<<(N + 63) / 64, 256, 0, stream>>>(X, W, B, H, N, flags);
  alpha_kernel<<<(N * 4 + 255) / 256, 256, 0, stream>>>(H, ATT, a_t, a_s, N, flags);
  edge_kernel<<<(E + 255) / 256, 256, 0, stream>>>(EIDX, (const f32x4*)a_t, (const f32x4*)a_s,
                                                   denom, cnt, E, flags);
  const int nb = (N + 255) / 256;
  scan_bsums<<<nb, 256, 0, stream>>>(cnt, bsum, N);
  scan_scan<<<1, 512, 0, stream>>>(bsum, nb);
  scan_final<<<nb, 256, 0, stream>>>(cnt, bsum, offsets, cursor, N);
  scatter_kernel<<<(E + 255) / 256, 256, 0, stream>>>(EIDX, cursor, s_src, E, flags);
  agg_kernel<<<(N + 3) / 4, 256, 0, stream>>>(H, s_src, a_t, a_s, offsets, cnt, denom,
                                              d_out, N, flags);
}

// Round 4
// 274.297 us; speedup vs baseline: 1.7896x; 1.7896x over previous
//
#include <hip/hip_runtime.h>

typedef unsigned short u16;
typedef unsigned int u32;
typedef __attribute__((ext_vector_type(8))) short short8;
typedef __attribute__((ext_vector_type(4))) float f32x4;
typedef __attribute__((ext_vector_type(2))) float f32x2;

__device__ __forceinline__ float b2f(u16 v) { return __uint_as_float(((u32)v) << 16); }
__device__ __forceinline__ u16 f2b(float f) {
  u32 x = __float_as_uint(f);
  return (u16)((x + 0x7FFFu + ((x >> 16) & 1u)) >> 16);  // round-nearest-even
}

// ---------------- runtime dtype detection (deterministic, graph-safe) ----------------
// flags[0]=1 if float inputs are bf16, 0 if fp32. flags[1]=1 if edge idx int64.
__global__ void detect_kernel(const u16* __restrict__ X16, const int* __restrict__ EIDX,
                              int* __restrict__ flags) {
  if (threadIdx.x != 0 || blockIdx.x != 0) return;
  int isb = 1;
  for (int i = 0; i < 32; i += 2) {
    const u16 v = X16[i];
    const u32 hb = (v >> 8) & 0x7f;
    if (!(v == 0 || (hb >= 0x32 && hb <= 0x41))) isb = 0;
  }
  int i64 = 1;
  for (int i = 1; i < 32; i += 2)
    if (EIDX[i] != 0) i64 = 0;
  flags[0] = isb;
  flags[1] = i64;
}

__global__ void sentinel_kernel(float* out) {
  if (threadIdx.x == 0 && blockIdx.x == 0) out[0] = 1.0e6f;  // ws too small marker
}

// ---------------- h = X @ W^T + b  (fp32 MFMA accum, bf16 H) ----------------
// LDS 128x128 u16 = 64 KB; XOR chunk swizzle keeps B-frag ds_read_b128 bank-balanced.
__global__ __launch_bounds__(256) void gemm_kernel(const void* __restrict__ Xv,
                                                   const void* __restrict__ Wv,
                                                   const void* __restrict__ Bv,
                                                   u16* __restrict__ H, int M,
                                                   const int* __restrict__ flags) {
  const int isb = flags[0];
  __shared__ u16 lw[128 * 128];
  const int tid = threadIdx.x;
  {
    const int row = tid >> 1, half = tid & 1;
    if (isb) {
      const u16* src = (const u16*)Wv + row * 128;
#pragma unroll
      for (int i = 0; i < 8; ++i) {
        const int c = half * 8 + i;
        *(short8*)&lw[row * 128 + ((c ^ (row & 15)) * 8)] = *(const short8*)(src + c * 8);
      }
    } else {
      const float* src = (const float*)Wv + row * 128;
#pragma unroll
      for (int i = 0; i < 8; ++i) {
        const int c = half * 8 + i;
        f32x4 a = *(const f32x4*)(src + c * 8);
        f32x4 b = *(const f32x4*)(src + c * 8 + 4);
        short8 o;
#pragma unroll
        for (int j = 0; j < 4; ++j) { o[j] = (short)f2b(a[j]); o[j + 4] = (short)f2b(b[j]); }
        *(short8*)&lw[row * 128 + ((c ^ (row & 15)) * 8)] = o;
      }
    }
  }
  __syncthreads();

  const int wave = tid >> 6, lane = tid & 63;
  const int q = lane >> 4, r = lane & 15;
  const int mfrag = blockIdx.x * 64 + wave * 16 + r;  // A-frag: m = lane&15, k = q*8+j
  const long msafe = (mfrag < M) ? mfrag : 0;

  f32x4 acc[8];
#pragma unroll
  for (int i = 0; i < 8; ++i) acc[i] = (f32x4){0.f, 0.f, 0.f, 0.f};

#pragma unroll
  for (int kk = 0; kk < 4; ++kk) {
    short8 a;
    if (isb) {
      a = *(const short8*)((const u16*)Xv + msafe * 128 + kk * 32 + q * 8);
    } else {
      const float* xp = (const float*)Xv + msafe * 128 + kk * 32 + q * 8;
      f32x4 x0 = *(const f32x4*)xp;
      f32x4 x1 = *(const f32x4*)(xp + 4);
#pragma unroll
      for (int j = 0; j < 4; ++j) { a[j] = (short)f2b(x0[j]); a[j + 4] = (short)f2b(x1[j]); }
    }
#pragma unroll
    for (int nt = 0; nt < 8; ++nt) {
      short8 b = *(const short8*)&lw[(nt * 16 + r) * 128 + (((kk * 4 + q) ^ r) * 8)];
      acc[nt] = __builtin_amdgcn_mfma_f32_16x16x32_bf16(a, b, acc[nt], 0, 0, 0);
    }
  }

  const int mbase = blockIdx.x * 64 + wave * 16 + q * 4;  // C/D: col=lane&15, row=q*4+reg
#pragma unroll
  for (int nt = 0; nt < 8; ++nt) {
    const int n = nt * 16 + r;
    const float bn = isb ? b2f(((const u16*)Bv)[n]) : ((const float*)Bv)[n];
#pragma unroll
    for (int rr = 0; rr < 4; ++rr) {
      const int m = mbase + rr;
      if (m < M) H[(long)m * 128 + n] = f2b(acc[nt][rr] + bn);
    }
  }
}

// ---------------- per-(node,head): ea_t = exp(0.01*<h,att_t>), ea_s likewise ----------
__global__ __launch_bounds__(256) void alpha_kernel(const u16* __restrict__ H,
                                                    const void* __restrict__ ATTv,
                                                    float* __restrict__ ea_t,
                                                    float* __restrict__ ea_s, int N,
                                                    const int* __restrict__ flags) {
  const int isb = flags[0];
  const int tid = blockIdx.x * 256 + threadIdx.x;
  if (tid >= N * 4) return;
  const int node = tid >> 2, head = tid & 3;
  const u16* hp = H + (long)node * 128 + head * 32;
  const u16* a16 = (const u16*)ATTv + head * 64;
  const float* a32 = (const float*)ATTv + head * 64;
  float st = 0.f, ss = 0.f;
#pragma unroll
  for (int v = 0; v < 4; ++v) {
    short8 hv = *(const short8*)(hp + v * 8);
#pragma unroll
    for (int j = 0; j < 8; ++j) {
      const int k = v * 8 + j;
      const float x = b2f((u16)hv[j]);
      st += x * (isb ? b2f(a16[k]) : a32[k]);
      ss += x * (isb ? b2f(a16[32 + k]) : a32[32 + k]);
    }
  }
  ea_t[tid] = __expf(0.01f * st);
  ea_s[tid] = __expf(0.01f * ss);
}

// ---------------- per-edge: in-degree histogram + stable rank (THE only atomics) ------
__global__ __launch_bounds__(256) void rank_kernel(const int* __restrict__ EIDX,
                                                   int* __restrict__ cnt,
                                                   int* __restrict__ rank, int E,
                                                   const int* __restrict__ flags) {
  const int i64 = flags[1];
  const int e = blockIdx.x * 256 + threadIdx.x;
  if (e >= E) return;
  const int t = i64 ? EIDX[2 * E + 2 * e] : EIDX[E + e];
  rank[e] = atomicAdd(&cnt[t], 1);
}

// ---------------- counting-sort scan (3 phases) ----------------
__global__ __launch_bounds__(256) void scan_bsums(const int* __restrict__ cnt,
                                                  int* __restrict__ bsum, int N) {
  __shared__ int s[256];
  const int i = blockIdx.x * 256 + threadIdx.x;
  s[threadIdx.x] = (i < N) ? cnt[i] : 0;
  __syncthreads();
  for (int o = 128; o > 0; o >>= 1) {
    if (threadIdx.x < o) s[threadIdx.x] += s[threadIdx.x + o];
    __syncthreads();
  }
  if (threadIdx.x == 0) bsum[blockIdx.x] = s[0];
}

__global__ __launch_bounds__(512) void scan_scan(int* bsum, int nb) {
  __shared__ int s[512];
  const int t = threadIdx.x;
  s[t] = (t < nb) ? bsum[t] : 0;
  __syncthreads();
  for (int o = 1; o < 512; o <<= 1) {
    const int x = (t >= o) ? s[t - o] : 0;
    __syncthreads();
    s[t] += x;
    __syncthreads();
  }
  if (t < nb) bsum[t] = (t == 0) ? 0 : s[t - 1];  // exclusive
}

__global__ __launch_bounds__(256) void scan_final(const int* __restrict__ cnt,
                                                  const int* __restrict__ bbase,
                                                  int* __restrict__ offsets, int N) {
  __shared__ int s[256];
  const int i = blockIdx.x * 256 + threadIdx.x;
  const int t = threadIdx.x;
  const int v = (i < N) ? cnt[i] : 0;
  s[t] = v;
  __syncthreads();
  for (int o = 1; o < 256; o <<= 1) {
    const int x = (t >= o) ? s[t - o] : 0;
    __syncthreads();
    s[t] += x;
    __syncthreads();
  }
  if (i < N) offsets[i] = s[t] - v + bbase[blockIdx.x];
}

// ---------------- bucket edges by target (atomic-free: uses saved rank) ----------------
__global__ __launch_bounds__(256) void place_kernel(const int* __restrict__ EIDX,
                                                    const int* __restrict__ rank,
                                                    const int* __restrict__ offsets,
                                                    int* __restrict__ s_src, int E,
                                                    const int* __restrict__ flags) {
  const int i64 = flags[1];
  const int e = blockIdx.x * 256 + threadIdx.x;
  if (e >= E) return;
  const int s = i64 ? EIDX[2 * e] : EIDX[e];
  const int t = i64 ? EIDX[2 * E + 2 * e] : EIDX[E + e];
  s_src[offsets[t] + rank[e]] = s;
}

// ---------------- per-node single-pass aggregation + head mean ----------------
// out[t] = ea_t*S1/(ea_t*S0 + EPS), S1 = sum ea_s[s]*h[s], S0 = sum ea_s[s].
// wave per node; lane holds channels {2*lane, 2*lane+1}; head = lane>>4.
__global__ __launch_bounds__(256) void agg_kernel(const u16* __restrict__ H,
                                                  const int* __restrict__ s_src,
                                                  const float* __restrict__ ea_t,
                                                  const float* __restrict__ ea_s,
                                                  const int* __restrict__ offsets,
                                                  const int* __restrict__ cnt,
                                                  void* __restrict__ OUTv, int N,
                                                  const int* __restrict__ flags) {
  const int isb = flags[0];
  const int node = blockIdx.x * 4 + (threadIdx.x >> 6);
  if (node >= N) return;  // wave-uniform exit
  const int lane = threadIdx.x & 63;
  const int h = lane >> 4, c16 = lane & 15;
  const int start = offsets[node];
  const int deg = cnt[node];
  float acc0 = 0.f, acc1 = 0.f, s0 = 0.f;

  for (int base = 0; base < deg; base += 16) {
    const int m = deg - base;
    const int n16 = (m < 16) ? m : 16;
    // preload 16 edges: each lane mirrors edge (lane&15); one 64B line for the wave
    const int slot = base + c16;
    const int srcv = s_src[start + ((slot < deg) ? slot : (deg - 1))];
    const float eav = (slot < deg) ? ea_s[srcv * 4 + h] : 0.f;  // lane's own head
    for (int i = 0; i < n16; ++i) {
      const int src = __shfl(srcv, i);                 // edge i's source node
      const float ea = __shfl(eav, (lane & 48) | i);   // edge i, this lane's head
      const u32 hv = *(const u32*)(H + (size_t)src * 128 + lane * 2);
      acc0 += ea * b2f((u16)(hv & 0xFFFFu));
      acc1 += ea * b2f((u16)(hv >> 16));
      s0 += ea;
    }
  }

  const float et = ea_t[node * 4 + h];
  const float scale = et / (et * s0 + 1e-8f);
  acc0 *= scale;
  acc1 *= scale;
  // mean over 4 heads: lanes {c, c+16, c+32, c+48} hold the same channel pair
  acc0 += __shfl_xor(acc0, 16);
  acc0 += __shfl_xor(acc0, 32);
  acc1 += __shfl_xor(acc1, 16);
  acc1 += __shfl_xor(acc1, 32);
  if (lane < 16) {
    if (isb) {
      const u32 o = (u32)f2b(acc0 * 0.25f) | ((u32)f2b(acc1 * 0.25f) << 16);
      *(u32*)((u16*)OUTv + (size_t)node * 32 + lane * 2) = o;
    } else {
      *(f32x2*)((float*)OUTv + (size_t)node * 32 + lane * 2) = (f32x2){acc0 * 0.25f, acc1 * 0.25f};
    }
  }
}

extern "C" void kernel_launch(void* const* d_in, const int* in_sizes, int n_in,
                              void* d_out, int out_size, void* d_ws, size_t ws_size,
                              hipStream_t stream) {
  const void* X = d_in[0];
  const int* EIDX = (const int*)d_in[1];
  const void* W = d_in[2];
  const void* B = d_in[3];
  const void* ATT = d_in[4];

  const int N = in_sizes[0] / 128;
  const int E = in_sizes[1] / 2;

  char* ws = (char*)d_ws;
  size_t off = 0;
  auto alloc = [&](size_t bytes) {
    void* p = ws + off;
    off += (bytes + 255) & ~(size_t)255;
    return p;
  };
  u16* H = (u16*)alloc((size_t)N * 128 * 2);       // 25.6 MB
  float* ea_t = (float*)alloc((size_t)N * 4 * 4);  // 1.6 MB
  float* ea_s = (float*)alloc((size_t)N * 4 * 4);  // 1.6 MB
  int* cnt = (int*)alloc((size_t)N * 4);           // 0.4 MB
  int* bsum = (int*)alloc(4096);
  int* offsets = (int*)alloc((size_t)N * 4);       // 0.4 MB
  int* rank = (int*)alloc((size_t)E * 4);          // 3.2 MB
  int* s_src = (int*)alloc((size_t)E * 4);         // 3.2 MB
  int* flags = (int*)alloc(256);                   // total ~36 MB

  if (ws_size < off) {  // diagnostic path: absmax would show ~1e6, not NaN
    hipMemsetAsync(d_out, 0, (size_t)out_size * 2, stream);
    sentinel_kernel<<<1, 64, 0, stream>>>((float*)d_out);
    return;
  }

  hipMemsetAsync(cnt, 0, (size_t)N * 4, stream);

  detect_kernel<<<1, 64, 0, stream>>>((const u16*)X, EIDX, flags);
  gemm_kernel<<<(N + 63) / 64, 256, 0, stream>>>(X, W, B, H, N, flags);
  alpha_kernel<<<(N * 4 + 255) / 256, 256, 0, stream>>>(H, ATT, ea_t, ea_s, N, flags);
  rank_kernel<<<(E + 255) / 256, 256, 0, stream>>>(EIDX, cnt, rank, E, flags);
  const int nb = (N + 255) / 256;
  scan_bsums<<<nb, 256, 0, stream>>>(cnt, bsum, N);
  scan_scan<<<1, 512, 0, stream>>>(bsum, nb);
  scan_final<<<nb, 256, 0, stream>>>(cnt, bsum, offsets, N);
  place_kernel<<<(E + 255) / 256, 256, 0, stream>>>(EIDX, rank, offsets, s_src, E, flags);
  agg_kernel<<<(N + 3) / 4, 256, 0, stream>>>(H, s_src, ea_t, ea_s, offsets, cnt,
                                              d_out, N, flags);
}

// Round 6
// 269.117 us; speedup vs baseline: 1.8240x; 1.0192x over previous
//
#include <hip/hip_runtime.h>

typedef unsigned short u16;
typedef unsigned int u32;
typedef __attribute__((ext_vector_type(8))) short short8;
typedef __attribute__((ext_vector_type(4))) float f32x4;
typedef __attribute__((ext_vector_type(2))) float f32x2;

__device__ __forceinline__ float b2f(u16 v) { return __uint_as_float(((u32)v) << 16); }
__device__ __forceinline__ u16 f2b(float f) {
  u32 x = __float_as_uint(f);
  return (u16)((x + 0x7FFFu + ((x >> 16) & 1u)) >> 16);  // round-nearest-even
}

// ---------------- runtime dtype detection (deterministic, graph-safe) ----------------
// flags[0]=1 if float inputs are bf16, 0 if fp32. flags[1]=1 if edge idx int64.
__global__ void detect_kernel(const u16* __restrict__ X16, const int* __restrict__ EIDX,
                              int* __restrict__ flags) {
  if (threadIdx.x != 0 || blockIdx.x != 0) return;
  int isb = 1;
  for (int i = 0; i < 32; i += 2) {
    const u16 v = X16[i];
    const u32 hb = (v >> 8) & 0x7f;
    if (!(v == 0 || (hb >= 0x32 && hb <= 0x41))) isb = 0;
  }
  int i64 = 1;
  for (int i = 1; i < 32; i += 2)
    if (EIDX[i] != 0) i64 = 0;
  flags[0] = isb;
  flags[1] = i64;
}

__global__ void sentinel_kernel(float* out) {
  if (threadIdx.x == 0 && blockIdx.x == 0) out[0] = 1.0e6f;  // ws too small marker
}

// ---------------- h = X @ W^T + b  (fp32 MFMA accum, bf16 H) ----------------
// LDS 128x128 u16 = 64 KB; XOR chunk swizzle keeps B-frag ds_read_b128 bank-balanced.
__global__ __launch_bounds__(256) void gemm_kernel(const void* __restrict__ Xv,
                                                   const void* __restrict__ Wv,
                                                   const void* __restrict__ Bv,
                                                   u16* __restrict__ H, int M,
                                                   const int* __restrict__ flags) {
  const int isb = flags[0];
  __shared__ u16 lw[128 * 128];
  const int tid = threadIdx.x;
  {
    const int row = tid >> 1, half = tid & 1;
    if (isb) {
      const u16* src = (const u16*)Wv + row * 128;
#pragma unroll
      for (int i = 0; i < 8; ++i) {
        const int c = half * 8 + i;
        *(short8*)&lw[row * 128 + ((c ^ (row & 15)) * 8)] = *(const short8*)(src + c * 8);
      }
    } else {
      const float* src = (const float*)Wv + row * 128;
#pragma unroll
      for (int i = 0; i < 8; ++i) {
        const int c = half * 8 + i;
        f32x4 a = *(const f32x4*)(src + c * 8);
        f32x4 b = *(const f32x4*)(src + c * 8 + 4);
        short8 o;
#pragma unroll
        for (int j = 0; j < 4; ++j) { o[j] = (short)f2b(a[j]); o[j + 4] = (short)f2b(b[j]); }
        *(short8*)&lw[row * 128 + ((c ^ (row & 15)) * 8)] = o;
      }
    }
  }
  __syncthreads();

  const int wave = tid >> 6, lane = tid & 63;
  const int q = lane >> 4, r = lane & 15;
  const int mfrag = blockIdx.x * 64 + wave * 16 + r;  // A-frag: m = lane&15, k = q*8+j
  const long msafe = (mfrag < M) ? mfrag : 0;

  f32x4 acc[8];
#pragma unroll
  for (int i = 0; i < 8; ++i) acc[i] = (f32x4){0.f, 0.f, 0.f, 0.f};

#pragma unroll
  for (int kk = 0; kk < 4; ++kk) {
    short8 a;
    if (isb) {
      a = *(const short8*)((const u16*)Xv + msafe * 128 + kk * 32 + q * 8);
    } else {
      const float* xp = (const float*)Xv + msafe * 128 + kk * 32 + q * 8;
      f32x4 x0 = *(const f32x4*)xp;
      f32x4 x1 = *(const f32x4*)(xp + 4);
#pragma unroll
      for (int j = 0; j < 4; ++j) { a[j] = (short)f2b(x0[j]); a[j + 4] = (short)f2b(x1[j]); }
    }
#pragma unroll
    for (int nt = 0; nt < 8; ++nt) {
      short8 b = *(const short8*)&lw[(nt * 16 + r) * 128 + (((kk * 4 + q) ^ r) * 8)];
      acc[nt] = __builtin_amdgcn_mfma_f32_16x16x32_bf16(a, b, acc[nt], 0, 0, 0);
    }
  }

  const int mbase = blockIdx.x * 64 + wave * 16 + q * 4;  // C/D: col=lane&15, row=q*4+reg
#pragma unroll
  for (int nt = 0; nt < 8; ++nt) {
    const int n = nt * 16 + r;
    const float bn = isb ? b2f(((const u16*)Bv)[n]) : ((const float*)Bv)[n];
#pragma unroll
    for (int rr = 0; rr < 4; ++rr) {
      const int m = mbase + rr;
      if (m < M) H[(long)m * 128 + n] = f2b(acc[nt][rr] + bn);
    }
  }
}

// ---------------- per-(node,head): ea_t = exp(0.01*<h,att_t>), ea_s likewise ----------
__global__ __launch_bounds__(256) void alpha_kernel(const u16* __restrict__ H,
                                                    const void* __restrict__ ATTv,
                                                    float* __restrict__ ea_t,
                                                    float* __restrict__ ea_s, int N,
                                                    const int* __restrict__ flags) {
  const int isb = flags[0];
  const int tid = blockIdx.x * 256 + threadIdx.x;
  if (tid >= N * 4) return;
  const int node = tid >> 2, head = tid & 3;
  const u16* hp = H + (long)node * 128 + head * 32;
  const u16* a16 = (const u16*)ATTv + head * 64;
  const float* a32 = (const float*)ATTv + head * 64;
  float st = 0.f, ss = 0.f;
#pragma unroll
  for (int v = 0; v < 4; ++v) {
    short8 hv = *(const short8*)(hp + v * 8);
#pragma unroll
    for (int j = 0; j < 8; ++j) {
      const int k = v * 8 + j;
      const float x = b2f((u16)hv[j]);
      st += x * (isb ? b2f(a16[k]) : a32[k]);
      ss += x * (isb ? b2f(a16[32 + k]) : a32[32 + k]);
    }
  }
  ea_t[tid] = __expf(0.01f * st);
  ea_s[tid] = __expf(0.01f * ss);
}

// ---------------- per-edge: in-degree histogram + stable rank (the only atomics) ------
__global__ __launch_bounds__(256) void rank_kernel(const int* __restrict__ EIDX,
                                                   int* __restrict__ cnt,
                                                   int* __restrict__ rank, int E,
                                                   const int* __restrict__ flags) {
  const int i64 = flags[1];
  const int e = blockIdx.x * 256 + threadIdx.x;
  if (e >= E) return;
  const int t = i64 ? EIDX[2 * E + 2 * e] : EIDX[E + e];
  rank[e] = atomicAdd(&cnt[t], 1);
}

// ---------------- counting-sort scan (3 phases) ----------------
__global__ __launch_bounds__(256) void scan_bsums(const int* __restrict__ cnt,
                                                  int* __restrict__ bsum, int N) {
  __shared__ int s[256];
  const int i = blockIdx.x * 256 + threadIdx.x;
  s[threadIdx.x] = (i < N) ? cnt[i] : 0;
  __syncthreads();
  for (int o = 128; o > 0; o >>= 1) {
    if (threadIdx.x < o) s[threadIdx.x] += s[threadIdx.x + o];
    __syncthreads();
  }
  if (threadIdx.x == 0) bsum[blockIdx.x] = s[0];
}

__global__ __launch_bounds__(512) void scan_scan(int* bsum, int nb) {
  __shared__ int s[512];
  const int t = threadIdx.x;
  s[t] = (t < nb) ? bsum[t] : 0;
  __syncthreads();
  for (int o = 1; o < 512; o <<= 1) {
    const int x = (t >= o) ? s[t - o] : 0;
    __syncthreads();
    s[t] += x;
    __syncthreads();
  }
  if (t < nb) bsum[t] = (t == 0) ? 0 : s[t - 1];  // exclusive
}

__global__ __launch_bounds__(256) void scan_final(const int* __restrict__ cnt,
                                                  const int* __restrict__ bbase,
                                                  int* __restrict__ offsets, int N) {
  __shared__ int s[256];
  const int i = blockIdx.x * 256 + threadIdx.x;
  const int t = threadIdx.x;
  const int v = (i < N) ? cnt[i] : 0;
  s[t] = v;
  __syncthreads();
  for (int o = 1; o < 256; o <<= 1) {
    const int x = (t >= o) ? s[t - o] : 0;
    __syncthreads();
    s[t] += x;
    __syncthreads();
  }
  if (i < N) offsets[i] = s[t] - v + bbase[blockIdx.x];
}

// ---------------- bucket edges by target; also materialize sorted ea ----------------
__global__ __launch_bounds__(256) void place_kernel(const int* __restrict__ EIDX,
                                                    const int* __restrict__ rank,
                                                    const int* __restrict__ offsets,
                                                    const float* __restrict__ ea_s,
                                                    int* __restrict__ s_src,
                                                    f32x4* __restrict__ s_ea, int E,
                                                    const int* __restrict__ flags) {
  const int i64 = flags[1];
  const int e = blockIdx.x * 256 + threadIdx.x;
  if (e >= E) return;
  const int s = i64 ? EIDX[2 * e] : EIDX[e];
  const int t = i64 ? EIDX[2 * E + 2 * e] : EIDX[E + e];
  const int pos = offsets[t] + rank[e];
  s_src[pos] = s;
  s_ea[pos] = *(const f32x4*)(ea_s + (size_t)s * 4);
}

// ---------------- per-node single-pass aggregation + head mean ----------------
// out[t] = mean_h( ea_t*S1[h] / (ea_t*S0[h] + EPS) ), S1 = sum ea_s*h, S0 = sum ea_s.
// Wave per node; lane reads bytes [2*lane, 2*lane+2) of each edge's 256 B H-row
// (head h = lane>>4). src is a wave-uniform broadcast load; ea comes per-lane from
// the SORTED s_ea array (no src->ea dependent hop, no shfl in the loop). Iterations
// are address-independent -> unroll x4 keeps >=4 row-gathers in flight.
// Since all 16 lanes of quarter h read the same ea, s0 += ea directly yields S0[h].
__global__ __launch_bounds__(512) void agg_kernel(const u16* __restrict__ H,
                                                  const int* __restrict__ s_src,
                                                  const float* __restrict__ s_ea,
                                                  const float* __restrict__ ea_t,
                                                  const int* __restrict__ offsets,
                                                  const int* __restrict__ cnt,
                                                  void* __restrict__ OUTv, int N,
                                                  const int* __restrict__ flags) {
  const int isb = flags[0];
  const int node = blockIdx.x * 8 + (threadIdx.x >> 6);
  if (node >= N) return;  // wave-uniform exit
  const int lane = threadIdx.x & 63;
  const int h = lane >> 4;  // head; lane covers channels {2*lane, 2*lane+1}
  const int start = offsets[node];
  const int deg = cnt[node];

  float acc0 = 0.f, acc1 = 0.f, s0 = 0.f;
  int i = 0;
  for (; i + 4 <= deg; i += 4) {
#pragma unroll
    for (int j = 0; j < 4; ++j) {
      const int a = start + i + j;
      const int src = s_src[a];                  // wave-uniform broadcast load
      const float ea = s_ea[(size_t)a * 4 + h];  // quarter-uniform value
      const u32 hv = *(const u32*)(H + (size_t)src * 128 + lane * 2);
      acc0 += ea * b2f((u16)(hv & 0xFFFFu));
      acc1 += ea * b2f((u16)(hv >> 16));
      s0 += ea;
    }
  }
  for (; i < deg; ++i) {  // wave-uniform remainder
    const int a = start + i;
    const int src = s_src[a];
    const float ea = s_ea[(size_t)a * 4 + h];
    const u32 hv = *(const u32*)(H + (size_t)src * 128 + lane * 2);
    acc0 += ea * b2f((u16)(hv & 0xFFFFu));
    acc1 += ea * b2f((u16)(hv >> 16));
    s0 += ea;
  }

  const float et = ea_t[(size_t)node * 4 + h];
  const float scale = et / (et * s0 + 1e-8f);
  acc0 *= scale;
  acc1 *= scale;
  // mean over 4 heads: lanes {c, c+16, c+32, c+48} hold the same channel pair
  acc0 += __shfl_xor(acc0, 16);
  acc0 += __shfl_xor(acc0, 32);
  acc1 += __shfl_xor(acc1, 16);
  acc1 += __shfl_xor(acc1, 32);
  if (lane < 16) {
    if (isb) {
      const u32 o = (u32)f2b(acc0 * 0.25f) | ((u32)f2b(acc1 * 0.25f) << 16);
      *(u32*)((u16*)OUTv + (size_t)node * 32 + lane * 2) = o;
    } else {
      *(f32x2*)((float*)OUTv + (size_t)node * 32 + lane * 2) = (f32x2){acc0 * 0.25f, acc1 * 0.25f};
    }
  }
}

extern "C" void kernel_launch(void* const* d_in, const int* in_sizes, int n_in,
                              void* d_out, int out_size, void* d_ws, size_t ws_size,
                              hipStream_t stream) {
  const void* X = d_in[0];
  const int* EIDX = (const int*)d_in[1];
  const void* W = d_in[2];
  const void* B = d_in[3];
  const void* ATT = d_in[4];

  const int N = in_sizes[0] / 128;
  const int E = in_sizes[1] / 2;

  char* ws = (char*)d_ws;
  size_t off = 0;
  auto alloc = [&](size_t bytes) {
    void* p = ws + off;
    off += (bytes + 255) & ~(size_t)255;
    return p;
  };
  u16* H = (u16*)alloc((size_t)N * 128 * 2);       // 25.6 MB
  float* ea_t = (float*)alloc((size_t)N * 4 * 4);  // 1.6 MB
  float* ea_s = (float*)alloc((size_t)N * 4 * 4);  // 1.6 MB
  int* cnt = (int*)alloc((size_t)N * 4);           // 0.4 MB
  int* bsum = (int*)alloc(4096);
  int* offsets = (int*)alloc((size_t)N * 4);       // 0.4 MB
  int* rank = (int*)alloc((size_t)E * 4);          // 3.2 MB
  int* s_src = (int*)alloc((size_t)E * 4);         // 3.2 MB
  f32x4* s_ea = (f32x4*)alloc((size_t)E * 16);     // 12.8 MB
  int* flags = (int*)alloc(256);                   // total ~49 MB

  if (ws_size < off) {  // diagnostic path: absmax would show ~1e6, not NaN
    hipMemsetAsync(d_out, 0, (size_t)out_size * 2, stream);
    sentinel_kernel<<<1, 64, 0, stream>>>((float*)d_out);
    return;
  }

  hipMemsetAsync(cnt, 0, (size_t)N * 4, stream);

  detect_kernel<<<1, 64, 0, stream>>>((const u16*)X, EIDX, flags);
  gemm_kernel<<<(N + 63) / 64, 256, 0, stream>>>(X, W, B, H, N, flags);
  alpha_kernel<<<(N * 4 + 255) / 256, 256, 0, stream>>>(H, ATT, ea_t, ea_s, N, flags);
  rank_kernel<<<(E + 255) / 256, 256, 0, stream>>>(EIDX, cnt, rank, E, flags);
  const int nb = (N + 255) / 256;
  scan_bsums<<<nb, 256, 0, stream>>>(cnt, bsum, N);
  scan_scan<<<1, 512, 0, stream>>>(bsum, nb);
  scan_final<<<nb, 256, 0, stream>>>(cnt, bsum, offsets, N);
  place_kernel<<<(E + 255) / 256, 256, 0, stream>>>(EIDX, rank, offsets, ea_s,
                                                    s_src, s_ea, E, flags);
  agg_kernel<<<(N + 7) / 8, 512, 0, stream>>>(H, s_src, (const float*)s_ea, ea_t,
                                              offsets, cnt, d_out, N, flags);
}

// Round 7
// 265.908 us; speedup vs baseline: 1.8460x; 1.0121x over previous
//
#include <hip/hip_runtime.h>

typedef unsigned short u16;
typedef unsigned int u32;
typedef __attribute__((ext_vector_type(8))) short short8;
typedef __attribute__((ext_vector_type(4))) float f32x4;
typedef __attribute__((ext_vector_type(2))) float f32x2;
typedef __attribute__((ext_vector_type(2))) u32 u32x2;

__device__ __forceinline__ float b2f(u16 v) { return __uint_as_float(((u32)v) << 16); }
__device__ __forceinline__ u16 f2b(float f) {
  u32 x = __float_as_uint(f);
  return (u16)((x + 0x7FFFu + ((x >> 16) & 1u)) >> 16);  // round-nearest-even
}

// ---------------- runtime dtype detection (deterministic, graph-safe) ----------------
// flags[0]=1 if float inputs are bf16, 0 if fp32. flags[1]=1 if edge idx int64.
__global__ void detect_kernel(const u16* __restrict__ X16, const int* __restrict__ EIDX,
                              int* __restrict__ flags) {
  if (threadIdx.x != 0 || blockIdx.x != 0) return;
  int isb = 1;
  for (int i = 0; i < 32; i += 2) {
    const u16 v = X16[i];
    const u32 hb = (v >> 8) & 0x7f;
    if (!(v == 0 || (hb >= 0x32 && hb <= 0x41))) isb = 0;
  }
  int i64 = 1;
  for (int i = 1; i < 32; i += 2)
    if (EIDX[i] != 0) i64 = 0;
  flags[0] = isb;
  flags[1] = i64;
}

__global__ void sentinel_kernel(float* out) {
  if (threadIdx.x == 0 && blockIdx.x == 0) out[0] = 1.0e6f;  // ws too small marker
}

// ---------------- h = X @ W^T + b  (fp32 MFMA accum, bf16 H) ----------------
// LDS 128x128 u16 = 64 KB; XOR chunk swizzle keeps B-frag ds_read_b128 bank-balanced.
__global__ __launch_bounds__(256) void gemm_kernel(const void* __restrict__ Xv,
                                                   const void* __restrict__ Wv,
                                                   const void* __restrict__ Bv,
                                                   u16* __restrict__ H, int M,
                                                   const int* __restrict__ flags) {
  const int isb = flags[0];
  __shared__ u16 lw[128 * 128];
  const int tid = threadIdx.x;
  {
    const int row = tid >> 1, half = tid & 1;
    if (isb) {
      const u16* src = (const u16*)Wv + row * 128;
#pragma unroll
      for (int i = 0; i < 8; ++i) {
        const int c = half * 8 + i;
        *(short8*)&lw[row * 128 + ((c ^ (row & 15)) * 8)] = *(const short8*)(src + c * 8);
      }
    } else {
      const float* src = (const float*)Wv + row * 128;
#pragma unroll
      for (int i = 0; i < 8; ++i) {
        const int c = half * 8 + i;
        f32x4 a = *(const f32x4*)(src + c * 8);
        f32x4 b = *(const f32x4*)(src + c * 8 + 4);
        short8 o;
#pragma unroll
        for (int j = 0; j < 4; ++j) { o[j] = (short)f2b(a[j]); o[j + 4] = (short)f2b(b[j]); }
        *(short8*)&lw[row * 128 + ((c ^ (row & 15)) * 8)] = o;
      }
    }
  }
  __syncthreads();

  const int wave = tid >> 6, lane = tid & 63;
  const int q = lane >> 4, r = lane & 15;
  const int mfrag = blockIdx.x * 64 + wave * 16 + r;  // A-frag: m = lane&15, k = q*8+j
  const long msafe = (mfrag < M) ? mfrag : 0;

  f32x4 acc[8];
#pragma unroll
  for (int i = 0; i < 8; ++i) acc[i] = (f32x4){0.f, 0.f, 0.f, 0.f};

#pragma unroll
  for (int kk = 0; kk < 4; ++kk) {
    short8 a;
    if (isb) {
      a = *(const short8*)((const u16*)Xv + msafe * 128 + kk * 32 + q * 8);
    } else {
      const float* xp = (const float*)Xv + msafe * 128 + kk * 32 + q * 8;
      f32x4 x0 = *(const f32x4*)xp;
      f32x4 x1 = *(const f32x4*)(xp + 4);
#pragma unroll
      for (int j = 0; j < 4; ++j) { a[j] = (short)f2b(x0[j]); a[j + 4] = (short)f2b(x1[j]); }
    }
#pragma unroll
    for (int nt = 0; nt < 8; ++nt) {
      short8 b = *(const short8*)&lw[(nt * 16 + r) * 128 + (((kk * 4 + q) ^ r) * 8)];
      acc[nt] = __builtin_amdgcn_mfma_f32_16x16x32_bf16(a, b, acc[nt], 0, 0, 0);
    }
  }

  const int mbase = blockIdx.x * 64 + wave * 16 + q * 4;  // C/D: col=lane&15, row=q*4+reg
#pragma unroll
  for (int nt = 0; nt < 8; ++nt) {
    const int n = nt * 16 + r;
    const float bn = isb ? b2f(((const u16*)Bv)[n]) : ((const float*)Bv)[n];
#pragma unroll
    for (int rr = 0; rr < 4; ++rr) {
      const int m = mbase + rr;
      if (m < M) H[(long)m * 128 + n] = f2b(acc[nt][rr] + bn);
    }
  }
}

// ---------------- per-(node,head): ea_t = exp(0.01*<h,att_t>), ea_s likewise ----------
__global__ __launch_bounds__(256) void alpha_kernel(const u16* __restrict__ H,
                                                    const void* __restrict__ ATTv,
                                                    float* __restrict__ ea_t,
                                                    float* __restrict__ ea_s, int N,
                                                    const int* __restrict__ flags) {
  const int isb = flags[0];
  const int tid = blockIdx.x * 256 + threadIdx.x;
  if (tid >= N * 4) return;
  const int node = tid >> 2, head = tid & 3;
  const u16* hp = H + (long)node * 128 + head * 32;
  const u16* a16 = (const u16*)ATTv + head * 64;
  const float* a32 = (const float*)ATTv + head * 64;
  float st = 0.f, ss = 0.f;
#pragma unroll
  for (int v = 0; v < 4; ++v) {
    short8 hv = *(const short8*)(hp + v * 8);
#pragma unroll
    for (int j = 0; j < 8; ++j) {
      const int k = v * 8 + j;
      const float x = b2f((u16)hv[j]);
      st += x * (isb ? b2f(a16[k]) : a32[k]);
      ss += x * (isb ? b2f(a16[32 + k]) : a32[32 + k]);
    }
  }
  ea_t[tid] = __expf(0.01f * st);
  ea_s[tid] = __expf(0.01f * ss);
}

// ---------------- per-edge: in-degree histogram + stable rank (the only atomics) ------
__global__ __launch_bounds__(256) void rank_kernel(const int* __restrict__ EIDX,
                                                   int* __restrict__ cnt,
                                                   int* __restrict__ rank, int E,
                                                   const int* __restrict__ flags) {
  const int i64 = flags[1];
  const int e = blockIdx.x * 256 + threadIdx.x;
  if (e >= E) return;
  const int t = i64 ? EIDX[2 * E + 2 * e] : EIDX[E + e];
  rank[e] = atomicAdd(&cnt[t], 1);
}

// ---------------- counting-sort scan (3 phases) ----------------
__global__ __launch_bounds__(256) void scan_bsums(const int* __restrict__ cnt,
                                                  int* __restrict__ bsum, int N) {
  __shared__ int s[256];
  const int i = blockIdx.x * 256 + threadIdx.x;
  s[threadIdx.x] = (i < N) ? cnt[i] : 0;
  __syncthreads();
  for (int o = 128; o > 0; o >>= 1) {
    if (threadIdx.x < o) s[threadIdx.x] += s[threadIdx.x + o];
    __syncthreads();
  }
  if (threadIdx.x == 0) bsum[blockIdx.x] = s[0];
}

__global__ __launch_bounds__(512) void scan_scan(int* bsum, int nb) {
  __shared__ int s[512];
  const int t = threadIdx.x;
  s[t] = (t < nb) ? bsum[t] : 0;
  __syncthreads();
  for (int o = 1; o < 512; o <<= 1) {
    const int x = (t >= o) ? s[t - o] : 0;
    __syncthreads();
    s[t] += x;
    __syncthreads();
  }
  if (t < nb) bsum[t] = (t == 0) ? 0 : s[t - 1];  // exclusive
}

__global__ __launch_bounds__(256) void scan_final(const int* __restrict__ cnt,
                                                  const int* __restrict__ bbase,
                                                  int* __restrict__ offsets, int N) {
  __shared__ int s[256];
  const int i = blockIdx.x * 256 + threadIdx.x;
  const int t = threadIdx.x;
  const int v = (i < N) ? cnt[i] : 0;
  s[t] = v;
  __syncthreads();
  for (int o = 1; o < 256; o <<= 1) {
    const int x = (t >= o) ? s[t - o] : 0;
    __syncthreads();
    s[t] += x;
    __syncthreads();
  }
  if (i < N) offsets[i] = s[t] - v + bbase[blockIdx.x];
}

// ---------------- bucket edges by target (atomic-free: uses saved rank) ----------------
__global__ __launch_bounds__(256) void place_kernel(const int* __restrict__ EIDX,
                                                    const int* __restrict__ rank,
                                                    const int* __restrict__ offsets,
                                                    int* __restrict__ s_src, int E,
                                                    const int* __restrict__ flags) {
  const int i64 = flags[1];
  const int e = blockIdx.x * 256 + threadIdx.x;
  if (e >= E) return;
  const int s = i64 ? EIDX[2 * e] : EIDX[e];
  const int t = i64 ? EIDX[2 * E + 2 * e] : EIDX[E + e];
  s_src[offsets[t] + rank[e]] = s;
}

// ---------------- per-node single-pass aggregation + head mean ----------------
// out[t] = mean_h( ea_t*S1[h] / (ea_t*S0[h] + EPS) ), S1 = sum ea_s*h, S0 = sum ea_s.
// Wave per node, TWO edges per iteration: half-wave (32 lanes) per edge, each lane
// loads 8 B = 4 channels (dwordx2 -> 512 B/instruction for the wave). head = sub>>3.
// ea comes from a dependent-but-parallel gather ea_s[src*4+head] (depth 2, same as H).
// All offsets are u32 (arrays < 4 GB) to avoid 64-bit address chains.
__global__ __launch_bounds__(512) void agg_kernel(const u16* __restrict__ H,
                                                  const int* __restrict__ s_src,
                                                  const float* __restrict__ ea_s,
                                                  const float* __restrict__ ea_t,
                                                  const int* __restrict__ offsets,
                                                  const int* __restrict__ cnt,
                                                  void* __restrict__ OUTv, int N,
                                                  const int* __restrict__ flags) {
  const int isb = flags[0];
  const int node = blockIdx.x * 8 + (threadIdx.x >> 6);
  if (node >= N) return;  // wave-uniform exit
  const int lane = threadIdx.x & 63;
  const int half = lane >> 5;  // which edge of the current pair
  const int sub = lane & 31;   // channel group: channels 4*sub .. 4*sub+3
  const int head = sub >> 3;
  const int start = offsets[node];
  const int deg = cnt[node];

  if (deg == 0) {  // wave-uniform: reference gives 0/(0+EPS) = 0
    if (lane < 8) {
      if (isb) *(u32x2*)((u16*)OUTv + (u32)node * 32 + lane * 4) = (u32x2){0u, 0u};
      else *(f32x4*)((float*)OUTv + (u32)node * 32 + lane * 4) = (f32x4){0.f, 0.f, 0.f, 0.f};
    }
    return;
  }

  float a0 = 0.f, a1 = 0.f, a2 = 0.f, a3 = 0.f, s0 = 0.f;
  const int iters = (deg + 1) >> 1;
#pragma unroll 2
  for (int i = 0; i < iters; ++i) {
    const int eix = 2 * i + half;
    const bool valid = eix < deg;
    const u32 a = (u32)start + (valid ? (u32)eix : 0u);
    const int src = s_src[a];
    float ea = ea_s[(u32)src * 4u + head];
    if (!valid) ea = 0.f;
    const u32x2 hv = *(const u32x2*)(H + (u32)src * 128u + sub * 4u);
    a0 += ea * b2f((u16)(hv[0] & 0xFFFFu));
    a1 += ea * b2f((u16)(hv[0] >> 16));
    a2 += ea * b2f((u16)(hv[1] & 0xFFFFu));
    a3 += ea * b2f((u16)(hv[1] >> 16));
    s0 += ea;
  }

  // merge the two half-wave edge streams (disjoint edge subsets, same channels)
  a0 += __shfl_xor(a0, 32);
  a1 += __shfl_xor(a1, 32);
  a2 += __shfl_xor(a2, 32);
  a3 += __shfl_xor(a3, 32);
  s0 += __shfl_xor(s0, 32);

  const float et = ea_t[(u32)node * 4u + head];
  const float scale = 0.25f * et / (et * s0 + 1e-8f);  // per-head softmax + 1/4 head mean
  a0 *= scale;
  a1 *= scale;
  a2 *= scale;
  a3 *= scale;

  // sum over heads: within-head channel 4*(sub&7)+j lives at lanes sub, sub^8, sub^16, sub^24
  a0 += __shfl_xor(a0, 8);
  a0 += __shfl_xor(a0, 16);
  a1 += __shfl_xor(a1, 8);
  a1 += __shfl_xor(a1, 16);
  a2 += __shfl_xor(a2, 8);
  a2 += __shfl_xor(a2, 16);
  a3 += __shfl_xor(a3, 8);
  a3 += __shfl_xor(a3, 16);

  if (lane < 8) {  // lane covers output channels 4*lane .. 4*lane+3
    if (isb) {
      const u32 lo = (u32)f2b(a0) | ((u32)f2b(a1) << 16);
      const u32 hi = (u32)f2b(a2) | ((u32)f2b(a3) << 16);
      *(u32x2*)((u16*)OUTv + (u32)node * 32 + lane * 4) = (u32x2){lo, hi};
    } else {
      *(f32x4*)((float*)OUTv + (u32)node * 32 + lane * 4) = (f32x4){a0, a1, a2, a3};
    }
  }
}

extern "C" void kernel_launch(void* const* d_in, const int* in_sizes, int n_in,
                              void* d_out, int out_size, void* d_ws, size_t ws_size,
                              hipStream_t stream) {
  const void* X = d_in[0];
  const int* EIDX = (const int*)d_in[1];
  const void* W = d_in[2];
  const void* B = d_in[3];
  const void* ATT = d_in[4];

  const int N = in_sizes[0] / 128;
  const int E = in_sizes[1] / 2;

  char* ws = (char*)d_ws;
  size_t off = 0;
  auto alloc = [&](size_t bytes) {
    void* p = ws + off;
    off += (bytes + 255) & ~(size_t)255;
    return p;
  };
  u16* H = (u16*)alloc((size_t)N * 128 * 2);       // 25.6 MB
  float* ea_t = (float*)alloc((size_t)N * 4 * 4);  // 1.6 MB
  float* ea_s = (float*)alloc((size_t)N * 4 * 4);  // 1.6 MB
  int* cnt = (int*)alloc((size_t)N * 4);           // 0.4 MB
  int* bsum = (int*)alloc(4096);
  int* offsets = (int*)alloc((size_t)N * 4);       // 0.4 MB
  int* rank = (int*)alloc((size_t)E * 4);          // 3.2 MB
  int* s_src = (int*)alloc((size_t)E * 4);         // 3.2 MB
  int* flags = (int*)alloc(256);                   // total ~36 MB

  if (ws_size < off) {  // diagnostic path: absmax would show ~1e6, not NaN
    hipMemsetAsync(d_out, 0, (size_t)out_size * 2, stream);
    sentinel_kernel<<<1, 64, 0, stream>>>((float*)d_out);
    return;
  }

  hipMemsetAsync(cnt, 0, (size_t)N * 4, stream);

  detect_kernel<<<1, 64, 0, stream>>>((const u16*)X, EIDX, flags);
  gemm_kernel<<<(N + 63) / 64, 256, 0, stream>>>(X, W, B, H, N, flags);
  alpha_kernel<<<(N * 4 + 255) / 256, 256, 0, stream>>>(H, ATT, ea_t, ea_s, N, flags);
  rank_kernel<<<(E + 255) / 256, 256, 0, stream>>>(EIDX, cnt, rank, E, flags);
  const int nb = (N + 255) / 256;
  scan_bsums<<<nb, 256, 0, stream>>>(cnt, bsum, N);
  scan_scan<<<1, 512, 0, stream>>>(bsum, nb);
  scan_final<<<nb, 256, 0, stream>>>(cnt, bsum, offsets, N);
  place_kernel<<<(E + 255) / 256, 256, 0, stream>>>(EIDX, rank, offsets, s_src, E, flags);
  agg_kernel<<<(N + 7) / 8, 512, 0, stream>>>(H, s_src, ea_s, ea_t, offsets, cnt,
                                              d_out, N, flags);
}

// Round 8
// 247.522 us; speedup vs baseline: 1.9831x; 1.0743x over previous
//
#include <hip/hip_runtime.h>

typedef unsigned short u16;
typedef unsigned int u32;
typedef unsigned long long u64;
typedef __attribute__((ext_vector_type(8))) short short8;
typedef __attribute__((ext_vector_type(4))) float f32x4;
typedef __attribute__((ext_vector_type(2))) float f32x2;
typedef __attribute__((ext_vector_type(4))) u32 u32x4;

__device__ __forceinline__ float b2f(u16 v) { return __uint_as_float(((u32)v) << 16); }
__device__ __forceinline__ u16 f2b(float f) {
  u32 x = __float_as_uint(f);
  return (u16)((x + 0x7FFFu + ((x >> 16) & 1u)) >> 16);  // round-nearest-even
}

// ---------------- runtime dtype detection (deterministic, graph-safe) ----------------
__global__ void detect_kernel(const u16* __restrict__ X16, const int* __restrict__ EIDX,
                              int* __restrict__ flags) {
  if (threadIdx.x != 0 || blockIdx.x != 0) return;
  int isb = 1;
  for (int i = 0; i < 32; i += 2) {
    const u16 v = X16[i];
    const u32 hb = (v >> 8) & 0x7f;
    if (!(v == 0 || (hb >= 0x32 && hb <= 0x41))) isb = 0;
  }
  int i64 = 1;
  for (int i = 1; i < 32; i += 2)
    if (EIDX[i] != 0) i64 = 0;
  flags[0] = isb;
  flags[1] = i64;
}

__global__ void sentinel_kernel(float* out) {
  if (threadIdx.x == 0 && blockIdx.x == 0) out[0] = 1.0e6f;  // ws too small marker
}

// ---------------- fused: h = X@W^T + b (MFMA)  +  edge rank/histogram ----------------
// Roles interleaved proportionally over the grid so rank's 800K atomics (TCC-side)
// overlap gemm's MFMA/LDS phase. Both depend only on kernel inputs.
__global__ __launch_bounds__(256) void gemm_rank_kernel(
    const void* __restrict__ Xv, const void* __restrict__ Wv, const void* __restrict__ Bv,
    u16* __restrict__ H, int M, const int* __restrict__ EIDX, int* __restrict__ cnt,
    int* __restrict__ rank, int E, int NBG, int GRID, const int* __restrict__ flags) {
  const int isb = flags[0];
  const u32 bx = blockIdx.x;
  const u32 c0 = (u32)(((u64)bx * (u64)NBG) / (u64)GRID);
  const u32 c1 = (u32)(((u64)(bx + 1) * (u64)NBG) / (u64)GRID);

  if (c1 == c0) {  // ---- rank role ----
    const int i64 = flags[1];
    const int e = (int)(bx - c1) * 256 + threadIdx.x;
    if (e < E) {
      const int t = i64 ? EIDX[2 * E + 2 * e] : EIDX[E + e];
      rank[e] = atomicAdd(&cnt[t], 1);
    }
    return;
  }

  // ---- gemm role: tile index c0 ----
  const int tile = (int)c0;
  __shared__ u16 lw[128 * 128];  // XOR chunk swizzle: bank-balanced B-frag reads
  const int tid = threadIdx.x;
  {
    const int row = tid >> 1, half = tid & 1;
    if (isb) {
      const u16* src = (const u16*)Wv + row * 128;
#pragma unroll
      for (int i = 0; i < 8; ++i) {
        const int c = half * 8 + i;
        *(short8*)&lw[row * 128 + ((c ^ (row & 15)) * 8)] = *(const short8*)(src + c * 8);
      }
    } else {
      const float* src = (const float*)Wv + row * 128;
#pragma unroll
      for (int i = 0; i < 8; ++i) {
        const int c = half * 8 + i;
        f32x4 a = *(const f32x4*)(src + c * 8);
        f32x4 b = *(const f32x4*)(src + c * 8 + 4);
        short8 o;
#pragma unroll
        for (int j = 0; j < 4; ++j) { o[j] = (short)f2b(a[j]); o[j + 4] = (short)f2b(b[j]); }
        *(short8*)&lw[row * 128 + ((c ^ (row & 15)) * 8)] = o;
      }
    }
  }
  __syncthreads();

  const int wave = tid >> 6, lane = tid & 63;
  const int q = lane >> 4, r = lane & 15;
  const int mfrag = tile * 64 + wave * 16 + r;  // A-frag: m = lane&15, k = q*8+j
  const long msafe = (mfrag < M) ? mfrag : 0;

  f32x4 acc[8];
#pragma unroll
  for (int i = 0; i < 8; ++i) acc[i] = (f32x4){0.f, 0.f, 0.f, 0.f};

#pragma unroll
  for (int kk = 0; kk < 4; ++kk) {
    short8 a;
    if (isb) {
      a = *(const short8*)((const u16*)Xv + msafe * 128 + kk * 32 + q * 8);
    } else {
      const float* xp = (const float*)Xv + msafe * 128 + kk * 32 + q * 8;
      f32x4 x0 = *(const f32x4*)xp;
      f32x4 x1 = *(const f32x4*)(xp + 4);
#pragma unroll
      for (int j = 0; j < 4; ++j) { a[j] = (short)f2b(x0[j]); a[j + 4] = (short)f2b(x1[j]); }
    }
#pragma unroll
    for (int nt = 0; nt < 8; ++nt) {
      short8 b = *(const short8*)&lw[(nt * 16 + r) * 128 + (((kk * 4 + q) ^ r) * 8)];
      acc[nt] = __builtin_amdgcn_mfma_f32_16x16x32_bf16(a, b, acc[nt], 0, 0, 0);
    }
  }

  const int mbase = tile * 64 + wave * 16 + q * 4;  // C/D: col=lane&15, row=q*4+reg
#pragma unroll
  for (int nt = 0; nt < 8; ++nt) {
    const int n = nt * 16 + r;
    const float bn = isb ? b2f(((const u16*)Bv)[n]) : ((const float*)Bv)[n];
#pragma unroll
    for (int rr = 0; rr < 4; ++rr) {
      const int m = mbase + rr;
      if (m < M) H[(long)m * 128 + n] = f2b(acc[nt][rr] + bn);
    }
  }
}

// ---------------- fused: per-(node,head) attention alphas + per-block cnt sums --------
__global__ __launch_bounds__(256) void alpha_bsums_kernel(
    const u16* __restrict__ H, const void* __restrict__ ATTv, float* __restrict__ ea_t,
    float* __restrict__ ea_s, int N, int NA, const int* __restrict__ cnt,
    int* __restrict__ bsum, const int* __restrict__ flags) {
  __shared__ int s[256];
  if ((int)blockIdx.x >= NA) {  // ---- bsums role ----
    const int bid = blockIdx.x - NA;
    const int i = bid * 256 + threadIdx.x;
    s[threadIdx.x] = (i < N) ? cnt[i] : 0;
    __syncthreads();
    for (int o = 128; o > 0; o >>= 1) {
      if (threadIdx.x < o) s[threadIdx.x] += s[threadIdx.x + o];
      __syncthreads();
    }
    if (threadIdx.x == 0) bsum[bid] = s[0];
    return;
  }
  // ---- alpha role ----
  const int isb = flags[0];
  const int tid = blockIdx.x * 256 + threadIdx.x;
  if (tid >= N * 4) return;
  const int node = tid >> 2, head = tid & 3;
  const u16* hp = H + (long)node * 128 + head * 32;
  const u16* a16 = (const u16*)ATTv + head * 64;
  const float* a32 = (const float*)ATTv + head * 64;
  float st = 0.f, ss = 0.f;
#pragma unroll
  for (int v = 0; v < 4; ++v) {
    short8 hv = *(const short8*)(hp + v * 8);
#pragma unroll
    for (int j = 0; j < 8; ++j) {
      const int k = v * 8 + j;
      const float x = b2f((u16)hv[j]);
      st += x * (isb ? b2f(a16[k]) : a32[k]);
      ss += x * (isb ? b2f(a16[32 + k]) : a32[32 + k]);
    }
  }
  ea_t[tid] = __expf(0.01f * st);
  ea_s[tid] = __expf(0.01f * ss);
}

__global__ __launch_bounds__(512) void scan_scan(int* bsum, int nb) {
  __shared__ int s[512];
  const int t = threadIdx.x;
  s[t] = (t < nb) ? bsum[t] : 0;
  __syncthreads();
  for (int o = 1; o < 512; o <<= 1) {
    const int x = (t >= o) ? s[t - o] : 0;
    __syncthreads();
    s[t] += x;
    __syncthreads();
  }
  if (t < nb) bsum[t] = (t == 0) ? 0 : s[t - 1];  // exclusive
}

__global__ __launch_bounds__(256) void scan_final(const int* __restrict__ cnt,
                                                  const int* __restrict__ bbase,
                                                  int* __restrict__ offsets, int N) {
  __shared__ int s[256];
  const int i = blockIdx.x * 256 + threadIdx.x;
  const int t = threadIdx.x;
  const int v = (i < N) ? cnt[i] : 0;
  s[t] = v;
  __syncthreads();
  for (int o = 1; o < 256; o <<= 1) {
    const int x = (t >= o) ? s[t - o] : 0;
    __syncthreads();
    s[t] += x;
    __syncthreads();
  }
  if (i < N) offsets[i] = s[t] - v + bbase[blockIdx.x];
}

// ---------------- bucket edges by target; materialize sorted src + ea ----------------
__global__ __launch_bounds__(256) void place_kernel(const int* __restrict__ EIDX,
                                                    const int* __restrict__ rank,
                                                    const int* __restrict__ offsets,
                                                    const float* __restrict__ ea_s,
                                                    int* __restrict__ s_src,
                                                    f32x4* __restrict__ s_ea, int E,
                                                    const int* __restrict__ flags) {
  const int i64 = flags[1];
  const int e = blockIdx.x * 256 + threadIdx.x;
  if (e >= E) return;
  const int s = i64 ? EIDX[2 * e] : EIDX[e];
  const int t = i64 ? EIDX[2 * E + 2 * e] : EIDX[E + e];
  const int pos = offsets[t] + rank[e];
  s_src[pos] = s;
  s_ea[pos] = *(const f32x4*)(ea_s + (size_t)s * 4);
}

// ---------------- per-node aggregation + head mean (quarter-wave, 4 edges/iter) ------
// out[t] = mean_h( ea_t*S1[h] / (ea_t*S0[h] + EPS) ).
// Wave per node; quarter (16 lanes) per edge; lane loads 16 B = 8 channels of the
// edge's 256 B H-row (head = sub>>2 is lane-uniform). src + ea come from SORTED
// sequential arrays (no dependent hop). 3 vmem instructions per 4 edges.
__global__ __launch_bounds__(512) void agg_kernel(const u16* __restrict__ H,
                                                  const int* __restrict__ s_src,
                                                  const float* __restrict__ s_ea,
                                                  const float* __restrict__ ea_t,
                                                  const int* __restrict__ offsets,
                                                  const int* __restrict__ cnt,
                                                  void* __restrict__ OUTv, int N,
                                                  const int* __restrict__ flags) {
  const int isb = flags[0];
  const int node = blockIdx.x * 8 + (threadIdx.x >> 6);
  if (node >= N) return;  // wave-uniform exit
  const int lane = threadIdx.x & 63;
  const int quarter = lane >> 4;  // which edge of the current 4
  const int sub = lane & 15;      // channels 8*sub .. 8*sub+7
  const int head = sub >> 2;      // (8*sub+j)>>5, lane-uniform
  const int start = offsets[node];
  const int deg = cnt[node];

  float ac[8] = {0.f, 0.f, 0.f, 0.f, 0.f, 0.f, 0.f, 0.f};
  float s0 = 0.f;
  const int iters = (deg + 3) >> 2;
#pragma unroll 2
  for (int i = 0; i < iters; ++i) {
    const int eix = 4 * i + quarter;
    const bool valid = eix < deg;
    const u32 a = (u32)start + (valid ? (u32)eix : 0u);
    const int src = s_src[a];                  // 4 distinct values/wave
    float ea = s_ea[a * 4u + head];            // sequential, 64 B/wave
    if (!valid) ea = 0.f;
    const u32x4 hv = *(const u32x4*)(H + (u32)src * 128u + sub * 8u);  // 16 B/lane
#pragma unroll
    for (int w = 0; w < 4; ++w) {
      ac[2 * w] += ea * b2f((u16)(hv[w] & 0xFFFFu));
      ac[2 * w + 1] += ea * b2f((u16)(hv[w] >> 16));
    }
    s0 += ea;
  }

  // merge the 4 quarter edge-streams (disjoint edges, identical channel coverage)
#pragma unroll
  for (int w = 0; w < 8; ++w) {
    ac[w] += __shfl_xor(ac[w], 16);
    ac[w] += __shfl_xor(ac[w], 32);
  }
  s0 += __shfl_xor(s0, 16);
  s0 += __shfl_xor(s0, 32);

  const float et = ea_t[(u32)node * 4u + head];
  const float scale = 0.25f * et / (et * s0 + 1e-8f);  // softmax + 1/4 head mean
#pragma unroll
  for (int w = 0; w < 8; ++w) ac[w] *= scale;

  // sum over heads: within-head channel 8*(sub&3)+j lives at lanes sub, sub^4, sub^8, sub^12
#pragma unroll
  for (int w = 0; w < 8; ++w) {
    ac[w] += __shfl_xor(ac[w], 4);
    ac[w] += __shfl_xor(ac[w], 8);
  }

  if (lane < 4) {  // lane covers output channels 8*lane .. 8*lane+7
    if (isb) {
      u32x4 o;
#pragma unroll
      for (int w = 0; w < 4; ++w)
        o[w] = (u32)f2b(ac[2 * w]) | ((u32)f2b(ac[2 * w + 1]) << 16);
      *(u32x4*)((u16*)OUTv + (u32)node * 32 + lane * 8) = o;
    } else {
      float* op = (float*)OUTv + (u32)node * 32 + lane * 8;
      *(f32x4*)op = (f32x4){ac[0], ac[1], ac[2], ac[3]};
      *(f32x4*)(op + 4) = (f32x4){ac[4], ac[5], ac[6], ac[7]};
    }
  }
}

extern "C" void kernel_launch(void* const* d_in, const int* in_sizes, int n_in,
                              void* d_out, int out_size, void* d_ws, size_t ws_size,
                              hipStream_t stream) {
  const void* X = d_in[0];
  const int* EIDX = (const int*)d_in[1];
  const void* W = d_in[2];
  const void* B = d_in[3];
  const void* ATT = d_in[4];

  const int N = in_sizes[0] / 128;
  const int E = in_sizes[1] / 2;

  char* ws = (char*)d_ws;
  size_t off = 0;
  auto alloc = [&](size_t bytes) {
    void* p = ws + off;
    off += (bytes + 255) & ~(size_t)255;
    return p;
  };
  u16* H = (u16*)alloc((size_t)N * 128 * 2);       // 25.6 MB
  float* ea_t = (float*)alloc((size_t)N * 4 * 4);  // 1.6 MB
  float* ea_s = (float*)alloc((size_t)N * 4 * 4);  // 1.6 MB
  int* cnt = (int*)alloc((size_t)N * 4);           // 0.4 MB
  int* bsum = (int*)alloc(4096);
  int* offsets = (int*)alloc((size_t)N * 4);       // 0.4 MB
  int* rank = (int*)alloc((size_t)E * 4);          // 3.2 MB
  int* s_src = (int*)alloc((size_t)E * 4);         // 3.2 MB
  f32x4* s_ea = (f32x4*)alloc((size_t)E * 16);     // 12.8 MB
  int* flags = (int*)alloc(256);                   // total ~49 MB

  if (ws_size < off) {  // diagnostic path: absmax would show ~1e6, not NaN
    hipMemsetAsync(d_out, 0, (size_t)out_size * 2, stream);
    sentinel_kernel<<<1, 64, 0, stream>>>((float*)d_out);
    return;
  }

  hipMemsetAsync(cnt, 0, (size_t)N * 4, stream);
  detect_kernel<<<1, 64, 0, stream>>>((const u16*)X, EIDX, flags);

  const int NBG = (N + 63) / 64;
  const int NBR = (E + 255) / 256;
  const int GRID = NBG + NBR;
  gemm_rank_kernel<<<GRID, 256, 0, stream>>>(X, W, B, H, N, EIDX, cnt, rank, E,
                                             NBG, GRID, flags);

  const int NA = (N * 4 + 255) / 256;
  const int nb = (N + 255) / 256;
  alpha_bsums_kernel<<<NA + nb, 256, 0, stream>>>(H, ATT, ea_t, ea_s, N, NA, cnt,
                                                  bsum, flags);
  scan_scan<<<1, 512, 0, stream>>>(bsum, nb);
  scan_final<<<nb, 256, 0, stream>>>(cnt, bsum, offsets, N);
  place_kernel<<<NBR, 256, 0, stream>>>(EIDX, rank, offsets, ea_s, s_src, s_ea, E, flags);
  agg_kernel<<<(N + 7) / 8, 512, 0, stream>>>(H, s_src, (const float*)s_ea, ea_t,
                                              offsets, cnt, d_out, N, flags);
}